// Round 1
// baseline (721.947 us; speedup 1.0000x reference)
//
#include <hip/hip_runtime.h>
#include <hip/hip_bf16.h>

// ConvSTFT as GEMM: C[b][c][f] = sum_k x_pad[b][f*100+k] * W[c][k]
// B=32, T=480000, WIN=400, HOP=100, C_OUT=514, PAD=300, NF=4803.
// Tile: 128 frames x 64 channels per block, 4 waves, each wave 32x64 via
// 2x4 grid of v_mfma_f32_16x16x32_bf16. K padded 400->416 (13 chunks).
// Stage raw x segment (frames overlap 4x) + weight tile in LDS as bf16.

#define T_LEN   480000
#define NF      4803
#define C_OUT   514
#define HOP     100
#define WIN     400
#define KP      416      // K padded to 13*32
#define BM      128      // frames per block
#define BN      64       // channels per block
#define SEG     13120    // staged x samples: (BM-1)*HOP + KP = 13116 -> pad 13120
#define WSTR    424      // w_s row stride (elements): 416 + 8 pad (bank-friendly, 16B-aligned)
#define MT_CNT  38       // ceil(4803/128)
#define NT_CNT  9        // ceil(514/64)

typedef __attribute__((ext_vector_type(8))) short short8;
typedef __attribute__((ext_vector_type(4))) float f32x4;

__device__ __forceinline__ unsigned short f2bf(float f) {
    unsigned int u = __float_as_uint(f);
    u += 0x7FFFu + ((u >> 16) & 1u);   // round-to-nearest-even
    return (unsigned short)(u >> 16);
}

__global__ __launch_bounds__(256, 2)
void conv_stft_kernel(const float* __restrict__ x,
                      const float* __restrict__ w,
                      float* __restrict__ out) {
    __shared__ short x_s[SEG];          // 26,240 B
    __shared__ short w_s[BN * WSTR];    // 54,272 B   (total 80,512 B -> 2 blocks/CU)

    const int tid = threadIdx.x;
    const int mt  = blockIdx.x;    // frame tile
    const int nt  = blockIdx.y;    // channel tile
    const int b   = blockIdx.z;    // batch

    // ---------------- stage x segment (fp32 global -> bf16 LDS) ----------------
    // padded coords p0 = mt*12800 ; x coords s0 = p0 - 300 (multiple of 4)
    const int s0 = mt * (BM * HOP) - 300;
    const float* xb = x + (size_t)b * T_LEN;
    for (int v = tid; v < SEG / 4; v += 256) {
        int g = s0 + v * 4;
        float f0, f1, f2, f3;
        if (g >= 0 && g + 3 < T_LEN) {
            const float4 f = *(const float4*)(xb + g);
            f0 = f.x; f1 = f.y; f2 = f.z; f3 = f.w;
        } else {
            f0 = (g + 0 >= 0 && g + 0 < T_LEN) ? xb[g + 0] : 0.f;
            f1 = (g + 1 >= 0 && g + 1 < T_LEN) ? xb[g + 1] : 0.f;
            f2 = (g + 2 >= 0 && g + 2 < T_LEN) ? xb[g + 2] : 0.f;
            f3 = (g + 3 >= 0 && g + 3 < T_LEN) ? xb[g + 3] : 0.f;
        }
        ushort4 h;
        h.x = f2bf(f0); h.y = f2bf(f1); h.z = f2bf(f2); h.w = f2bf(f3);
        *(ushort4*)(&x_s[v * 4]) = h;   // 8B store, 8B-aligned
    }

    // ---------------- stage weight tile (fp32 global -> bf16 LDS) --------------
    // 64 rows x 104 float4-slots (slots 100..103 = K-pad zeros)
    for (int s = tid; s < BN * 104; s += 256) {
        const int r  = s / 104;
        const int gk = s - r * 104;
        const int c  = nt * BN + r;
        ushort4 h = make_ushort4(0, 0, 0, 0);
        if (gk < 100 && c < C_OUT) {
            const float4 f = *(const float4*)(w + (size_t)c * WIN + gk * 4);
            h.x = f2bf(f.x); h.y = f2bf(f.y); h.z = f2bf(f.z); h.w = f2bf(f.w);
        }
        *(ushort4*)(&w_s[r * WSTR + gk * 4]) = h;
    }

    __syncthreads();

    // ---------------- MFMA main loop ----------------
    const int lane = tid & 63;
    const int wv   = tid >> 6;          // wave 0..3 -> frame rows [wv*32, wv*32+32)
    const int q    = lane >> 4;         // quad 0..3
    const int lm   = lane & 15;

    f32x4 acc[2][4];
    #pragma unroll
    for (int mi = 0; mi < 2; ++mi)
        #pragma unroll
        for (int ni = 0; ni < 4; ++ni)
            acc[mi][ni] = (f32x4){0.f, 0.f, 0.f, 0.f};

    // A: frame m = lane&15 (+subtile), k = q*8 + j    (offset elems: frame*100 + k)
    const int a0 = (wv * 32 + lm) * HOP + q * 8;
    const int a1 = a0 + 16 * HOP;
    // B: chan n = lane&15 (+subtile), k = q*8 + j
    int boff[4];
    #pragma unroll
    for (int ni = 0; ni < 4; ++ni) boff[ni] = (ni * 16 + lm) * WSTR + q * 8;

    #pragma unroll
    for (int kc = 0; kc < 13; ++kc) {
        const int k = kc * 32;
        // x_s frags: 8B-aligned only -> load as 2x u64
        union { short8 v; unsigned long long u[2]; } au0, au1;
        {
            const unsigned long long* p0 = (const unsigned long long*)(x_s + a0 + k);
            const unsigned long long* p1 = (const unsigned long long*)(x_s + a1 + k);
            au0.u[0] = p0[0]; au0.u[1] = p0[1];
            au1.u[0] = p1[0]; au1.u[1] = p1[1];
        }
        #pragma unroll
        for (int ni = 0; ni < 4; ++ni) {
            const short8 bf = *(const short8*)(&w_s[boff[ni] + k]);   // 16B-aligned
            acc[0][ni] = __builtin_amdgcn_mfma_f32_16x16x32_bf16(au0.v, bf, acc[0][ni], 0, 0, 0);
            acc[1][ni] = __builtin_amdgcn_mfma_f32_16x16x32_bf16(au1.v, bf, acc[1][ni], 0, 0, 0);
        }
    }

    // ---------------- epilogue: C/D row=(q*4+reg)=frame, col=(lane&15)=channel ----
    float* ob = out + (size_t)b * C_OUT * NF;
    const int f_base = mt * BM + wv * 32 + q * 4;
    const int c_base = nt * BN + lm;
    #pragma unroll
    for (int mi = 0; mi < 2; ++mi) {
        #pragma unroll
        for (int ni = 0; ni < 4; ++ni) {
            const int cg = c_base + ni * 16;
            if (cg < C_OUT) {
                float* op = ob + (size_t)cg * NF;
                #pragma unroll
                for (int r = 0; r < 4; ++r) {
                    const int fg = f_base + mi * 16 + r;
                    if (fg < NF) op[fg] = acc[mi][ni][r];
                }
            }
        }
    }
}

extern "C" void kernel_launch(void* const* d_in, const int* in_sizes, int n_in,
                              void* d_out, int out_size, void* d_ws, size_t ws_size,
                              hipStream_t stream) {
    const float* x = (const float*)d_in[0];   // [32, 480000] fp32
    const float* w = (const float*)d_in[1];   // [514, 1, 400] fp32
    float* out = (float*)d_out;               // [32, 514, 4803] fp32

    dim3 grid(MT_CNT, NT_CNT, 32);
    conv_stft_kernel<<<grid, 256, 0, stream>>>(x, w, out);
}

// Round 2
// 457.726 us; speedup vs baseline: 1.5772x; 1.5772x over previous
//
#include <hip/hip_runtime.h>
#include <hip/hip_bf16.h>

// ConvSTFT as GEMM: C[b][c][f] = sum_k x_pad[b][f*100+k] * W[c][k]
// B=32, T=480000, WIN=400, HOP=100, C_OUT=514, PAD=300, NF=4803.
//
// R2 structure:
//   k1: x fp32 -> padded bf16 copy in d_ws  (per-batch stride XPS, zeros in pads)
//   k2: w fp32 -> bf16, rows padded 400->424 (zero K-pad), 576 rows (zero tail)
//   k3: GEMM. Stage x-seg + w-tile via global_load_lds (16B, no VALU convert),
//       13x (8x mfma_f32_16x16x32_bf16) per wave, 128x64 tile per block.

#define T_LEN   480000
#define NF      4803
#define C_OUT   514
#define HOP     100
#define WIN     400
#define BM      128
#define BN      64
#define WSTR    424                 // padded K stride for wp rows
#define XPS     487040              // per-batch padded x length (elems)
#define XP_TOTAL (32 * XPS)         // 15,585,280 elems
#define WP_ROWS 576
#define WP_ELEMS (WP_ROWS * WSTR)   // 244,224
#define WP_BYTE_OFF ((size_t)XP_TOTAL * 2)   // wp offset inside d_ws
#define WS_NEEDED (WP_BYTE_OFF + (size_t)WP_ELEMS * 2)
#define MT_CNT  38
#define NT_CNT  9
#define XSEG    13312               // staged x elems (26 KiB + pad; need 13116)

typedef __attribute__((ext_vector_type(8))) short short8;
typedef __attribute__((ext_vector_type(4))) float f32x4;

__device__ __forceinline__ unsigned short f2bf(float f) {
    unsigned int u = __float_as_uint(f);
    u += 0x7FFFu + ((u >> 16) & 1u);   // RNE
    return (unsigned short)(u >> 16);
}

__device__ __forceinline__ void gl_lds16(const unsigned short* g, unsigned short* l) {
    __builtin_amdgcn_global_load_lds(
        (const __attribute__((address_space(1))) unsigned int*)(g),
        (__attribute__((address_space(3))) unsigned int*)(l), 16, 0, 0);
}

// ---------------- k1: x fp32 -> padded bf16 ----------------
// xp[b*XPS + i] = (300 <= i < 480300) ? bf16(x[b*T_LEN + i-300]) : 0
__global__ void cvt_x_kernel(const float* __restrict__ x, unsigned short* __restrict__ xp) {
    const int t = blockIdx.x * 256 + threadIdx.x;     // one ushort4 per thread
    const int b  = t / (XPS / 4);
    const int i4 = t - b * (XPS / 4);
    const int i  = i4 * 4;
    const int g  = i - 300;
    ushort4 h;
    if (g >= 0 && g + 3 < T_LEN) {
        const float4 f = *(const float4*)(x + (size_t)b * T_LEN + g);
        h.x = f2bf(f.x); h.y = f2bf(f.y); h.z = f2bf(f.z); h.w = f2bf(f.w);
    } else {
        const float* xb = x + (size_t)b * T_LEN;
        h.x = (g + 0 >= 0 && g + 0 < T_LEN) ? f2bf(xb[g + 0]) : 0;
        h.y = (g + 1 >= 0 && g + 1 < T_LEN) ? f2bf(xb[g + 1]) : 0;
        h.z = (g + 2 >= 0 && g + 2 < T_LEN) ? f2bf(xb[g + 2]) : 0;
        h.w = (g + 3 >= 0 && g + 3 < T_LEN) ? f2bf(xb[g + 3]) : 0;
    }
    *(ushort4*)(xp + (size_t)b * XPS + i) = h;
}

// ---------------- k2: w fp32 -> padded bf16 ----------------
__global__ void cvt_w_kernel(const float* __restrict__ w, unsigned short* __restrict__ wp) {
    const int t = blockIdx.x * 256 + threadIdx.x;     // one elem per thread
    if (t >= WP_ELEMS) return;
    const int c = t / WSTR;
    const int k = t - c * WSTR;
    wp[t] = (c < C_OUT && k < WIN) ? f2bf(w[(size_t)c * WIN + k]) : 0;
}

// ---------------- k3: GEMM ----------------
__global__ __launch_bounds__(256, 2)
void stft_gemm(const unsigned short* __restrict__ xp,
               const unsigned short* __restrict__ wp,
               float* __restrict__ out) {
    __shared__ unsigned short x_s[XSEG];          // 26,624 B
    __shared__ unsigned short w_s[BN * WSTR];     // 54,272 B  (total 80,896 B)

    const int tid  = threadIdx.x;
    const int lane = tid & 63;
    const int wv   = tid >> 6;
    const int nt   = blockIdx.x;     // channel tile (fastest: 9 blocks share x-seg)
    const int mt   = blockIdx.y;     // frame tile
    const int b    = blockIdx.z;     // batch

    // stage x segment: 26 chunks of 1024 B (64 lanes x 16 B)
    const unsigned short* xg = xp + (size_t)b * XPS + mt * (BM * HOP);
    #pragma unroll
    for (int c = wv; c < 26; c += 4) {
        const int idx = (c << 6) + lane;          // 16B units
        gl_lds16(xg + idx * 8, x_s + idx * 8);
    }
    // stage w tile: 53 chunks of 1024 B (64 rows x 424 elems, exact copy)
    const unsigned short* wg = wp + (size_t)nt * (BN * WSTR);
    #pragma unroll
    for (int c = wv; c < 53; c += 4) {
        const int idx = (c << 6) + lane;
        gl_lds16(wg + idx * 8, w_s + idx * 8);
    }
    __syncthreads();

    const int q  = lane >> 4;
    const int lm = lane & 15;

    f32x4 acc[2][4];
    #pragma unroll
    for (int mi = 0; mi < 2; ++mi)
        #pragma unroll
        for (int ni = 0; ni < 4; ++ni)
            acc[mi][ni] = (f32x4){0.f, 0.f, 0.f, 0.f};

    // A: frame m = wv*32 + lm (+16), k = q*8 + j  -> x_s[frame*100 + k]
    const int a0 = (wv * 32 + lm) * HOP + q * 8;
    const int a1 = a0 + 16 * HOP;
    // B: chan n = ni*16 + lm, k = q*8 + j -> w_s[n*WSTR + k]
    int boff[4];
    #pragma unroll
    for (int ni = 0; ni < 4; ++ni) boff[ni] = (ni * 16 + lm) * WSTR + q * 8;

    #pragma unroll
    for (int kc = 0; kc < 13; ++kc) {
        const int k = kc * 32;
        union { short8 v; unsigned long long u[2]; } au0, au1;
        {
            const unsigned long long* p0 = (const unsigned long long*)(x_s + a0 + k);
            const unsigned long long* p1 = (const unsigned long long*)(x_s + a1 + k);
            au0.u[0] = p0[0]; au0.u[1] = p0[1];
            au1.u[0] = p1[0]; au1.u[1] = p1[1];
        }
        #pragma unroll
        for (int ni = 0; ni < 4; ++ni) {
            const short8 bf = *(const short8*)(&w_s[boff[ni] + k]);   // 16B-aligned
            acc[0][ni] = __builtin_amdgcn_mfma_f32_16x16x32_bf16(au0.v, bf, acc[0][ni], 0, 0, 0);
            acc[1][ni] = __builtin_amdgcn_mfma_f32_16x16x32_bf16(au1.v, bf, acc[1][ni], 0, 0, 0);
        }
    }

    // epilogue: C/D row = q*4+reg = frame, col = lane&15 = channel
    float* ob = out + (size_t)b * C_OUT * NF;
    const int f_base = mt * BM + wv * 32 + q * 4;
    const int c_base = nt * BN + lm;
    #pragma unroll
    for (int mi = 0; mi < 2; ++mi) {
        const int fg = f_base + mi * 16;
        const bool fok = (fg + 3 < NF);
        #pragma unroll
        for (int ni = 0; ni < 4; ++ni) {
            const int cg = c_base + ni * 16;
            if (cg < C_OUT) {
                float* op = ob + (size_t)cg * NF + fg;
                if (fok) {
                    op[0] = acc[mi][ni][0]; op[1] = acc[mi][ni][1];
                    op[2] = acc[mi][ni][2]; op[3] = acc[mi][ni][3];
                } else {
                    #pragma unroll
                    for (int r = 0; r < 4; ++r)
                        if (fg + r < NF) op[r] = acc[mi][ni][r];
                }
            }
        }
    }
}

// ---------------- fallback (R1 kernel) if ws too small ----------------
#define SEG 13120
__global__ __launch_bounds__(256, 2)
void conv_stft_fallback(const float* __restrict__ x,
                        const float* __restrict__ w,
                        float* __restrict__ out) {
    __shared__ short x_s[SEG];
    __shared__ short w_s[BN * WSTR];
    const int tid = threadIdx.x;
    const int nt  = blockIdx.x;
    const int mt  = blockIdx.y;
    const int b   = blockIdx.z;
    const int s0 = mt * (BM * HOP) - 300;
    const float* xb = x + (size_t)b * T_LEN;
    for (int v = tid; v < SEG / 4; v += 256) {
        int g = s0 + v * 4;
        float f0, f1, f2, f3;
        if (g >= 0 && g + 3 < T_LEN) {
            const float4 f = *(const float4*)(xb + g);
            f0 = f.x; f1 = f.y; f2 = f.z; f3 = f.w;
        } else {
            f0 = (g + 0 >= 0 && g + 0 < T_LEN) ? xb[g + 0] : 0.f;
            f1 = (g + 1 >= 0 && g + 1 < T_LEN) ? xb[g + 1] : 0.f;
            f2 = (g + 2 >= 0 && g + 2 < T_LEN) ? xb[g + 2] : 0.f;
            f3 = (g + 3 >= 0 && g + 3 < T_LEN) ? xb[g + 3] : 0.f;
        }
        ushort4 h; h.x = f2bf(f0); h.y = f2bf(f1); h.z = f2bf(f2); h.w = f2bf(f3);
        *(ushort4*)(&x_s[v * 4]) = h;
    }
    for (int s = tid; s < BN * 106; s += 256) {
        const int r  = s / 106;
        const int gk = s - r * 106;
        const int c  = nt * BN + r;
        ushort4 h = make_ushort4(0, 0, 0, 0);
        if (gk < 100 && c < C_OUT) {
            const float4 f = *(const float4*)(w + (size_t)c * WIN + gk * 4);
            h.x = f2bf(f.x); h.y = f2bf(f.y); h.z = f2bf(f.z); h.w = f2bf(f.w);
        }
        if (gk * 4 < WSTR) *(ushort4*)(&w_s[r * WSTR + gk * 4]) = h;
    }
    __syncthreads();
    const int lane = tid & 63, wv = tid >> 6, q = lane >> 4, lm = lane & 15;
    f32x4 acc[2][4];
    #pragma unroll
    for (int mi = 0; mi < 2; ++mi)
        #pragma unroll
        for (int ni = 0; ni < 4; ++ni) acc[mi][ni] = (f32x4){0.f,0.f,0.f,0.f};
    const int a0 = (wv * 32 + lm) * HOP + q * 8;
    const int a1 = a0 + 16 * HOP;
    int boff[4];
    #pragma unroll
    for (int ni = 0; ni < 4; ++ni) boff[ni] = (ni * 16 + lm) * WSTR + q * 8;
    #pragma unroll
    for (int kc = 0; kc < 13; ++kc) {
        const int k = kc * 32;
        union { short8 v; unsigned long long u[2]; } au0, au1;
        const unsigned long long* p0 = (const unsigned long long*)(x_s + a0 + k);
        const unsigned long long* p1 = (const unsigned long long*)(x_s + a1 + k);
        au0.u[0] = p0[0]; au0.u[1] = p0[1];
        au1.u[0] = p1[0]; au1.u[1] = p1[1];
        #pragma unroll
        for (int ni = 0; ni < 4; ++ni) {
            const short8 bf = *(const short8*)(&w_s[boff[ni] + k]);
            acc[0][ni] = __builtin_amdgcn_mfma_f32_16x16x32_bf16(au0.v, bf, acc[0][ni], 0, 0, 0);
            acc[1][ni] = __builtin_amdgcn_mfma_f32_16x16x32_bf16(au1.v, bf, acc[1][ni], 0, 0, 0);
        }
    }
    float* ob = out + (size_t)b * C_OUT * NF;
    const int f_base = mt * BM + wv * 32 + q * 4;
    const int c_base = nt * BN + lm;
    #pragma unroll
    for (int mi = 0; mi < 2; ++mi) {
        #pragma unroll
        for (int ni = 0; ni < 4; ++ni) {
            const int cg = c_base + ni * 16;
            if (cg < C_OUT) {
                float* op = ob + (size_t)cg * NF;
                #pragma unroll
                for (int r = 0; r < 4; ++r) {
                    const int fg = f_base + mi * 16 + r;
                    if (fg < NF) op[fg] = acc[mi][ni][r];
                }
            }
        }
    }
}

extern "C" void kernel_launch(void* const* d_in, const int* in_sizes, int n_in,
                              void* d_out, int out_size, void* d_ws, size_t ws_size,
                              hipStream_t stream) {
    const float* x = (const float*)d_in[0];   // [32, 480000] fp32
    const float* w = (const float*)d_in[1];   // [514, 1, 400] fp32
    float* out = (float*)d_out;               // [32, 514, 4803] fp32

    if (ws_size >= WS_NEEDED) {
        unsigned short* xp = (unsigned short*)d_ws;
        unsigned short* wp = (unsigned short*)((char*)d_ws + WP_BYTE_OFF);
        cvt_x_kernel<<<XP_TOTAL / 4 / 256, 256, 0, stream>>>(x, xp);
        cvt_w_kernel<<<(WP_ELEMS + 255) / 256, 256, 0, stream>>>(w, wp);
        dim3 grid(NT_CNT, MT_CNT, 32);
        stft_gemm<<<grid, 256, 0, stream>>>(xp, wp, out);
    } else {
        dim3 grid(NT_CNT, MT_CNT, 32);
        conv_stft_fallback<<<grid, 256, 0, stream>>>(x, w, out);
    }
}